// Round 16
// baseline (2242.245 us; speedup 1.0000x reference)
//
#include <hip/hip_runtime.h>
#include <hip/hip_bf16.h>
#include <cstdio>
#include <math.h>

// ---------------------------------------------------------------------------
// StyleGANv2 generator forward. bf16 MFMA implicit-GEMM convolutions.
//   mod+demod conv == d[b,o] * conv(x * s'[b,i], w_shared); s' folded into the
//   producer epilogue so GEMM A-operand is a pure bf16 gather.
//   Up-conv: parity-decomposed (blockIdx.z = output parity class).
//   k_conv  (R14): 128x128, async global_load_lds double-buffer, vmcnt(8)
//   counted waits (loads in flight across barriers), zero-page border reads,
//   XOR-8 swizzle via pre-swizzled global SOURCE addresses. No setprio (R15
//   showed -2.5% in this lockstep pipeline).
//   k_conv2 (R16): same skeleton at 256x256, 512 thr, 8 waves 2Mx4N (wave
//   128x64, acc 8x4), LDS 128KB dbuf. LDS bytes/FLOP: 96KB->64KB per 2.1MFLOP
//   equiv => predicted MfmaUtil ~50-60% (vs the 38-40% cap measured for all
//   128^2 variants; LDS eff BW ~110 B/cyc/CU explains that cap).
//   k_blurF: fused separable blur (V -> LDS row buffer -> H + epilogue).
// ---------------------------------------------------------------------------

static constexpr int NB = 32;
static constexpr float SQRT2F      = 1.41421356237309515f;
static constexpr float INV_SQRT512 = 0.04419417382415922f;   // 1/sqrt(512)
static constexpr float INV_SQRT4608= 0.014731391274719742f;  // 1/sqrt(512*9)

typedef __hip_bfloat16 bf16;
typedef __attribute__((ext_vector_type(8))) short bf16x8;
typedef __attribute__((ext_vector_type(4))) float f32x4;

#define GLOAD_LDS16(src, dst) __builtin_amdgcn_global_load_lds( \
    (const __attribute__((address_space(1))) void*)(src), \
    (__attribute__((address_space(3))) void*)(dst), 16, 0, 0)

__device__ __forceinline__ float lrelu_s2(float v){ return (v > 0.f ? v : 0.2f*v) * SQRT2F; }
__device__ __forceinline__ float bf_lo(unsigned u){ unsigned v = u << 16; return __builtin_bit_cast(float, v); }
__device__ __forceinline__ float bf_hi(unsigned u){ unsigned v = u & 0xffff0000u; return __builtin_bit_cast(float, v); }
__device__ __forceinline__ unsigned packbf2(float a, float b){
  bf16 ha = __float2bfloat16(a), hb = __float2bfloat16(b);
  unsigned short ra = __builtin_bit_cast(unsigned short, ha);
  unsigned short rb = __builtin_bit_cast(unsigned short, hb);
  return (unsigned)ra | ((unsigned)rb << 16);
}

// ---------------- mapping network: pixel_norm + 8x (512x512 lrelu) ----------
__global__ void k_mapping(const float* __restrict__ z, const float* __restrict__ mlp_w,
                          const float* __restrict__ mlp_b, float* __restrict__ wlat){
  __shared__ float xb[512], yb[512], red[256];
  int b = blockIdx.x, t = threadIdx.x;
  float z0 = z[b*512 + t], z1 = z[b*512 + t + 256];
  red[t] = z0*z0 + z1*z1;
  __syncthreads();
  for(int s = 128; s > 0; s >>= 1){ if(t < s) red[t] += red[t+s]; __syncthreads(); }
  float norm = sqrtf(red[0]) * INV_SQRT512;
  float inv = 1.f / (norm + 1e-6f);
  xb[t] = z0*inv; xb[t+256] = z1*inv;
  __syncthreads();
  for(int l = 0; l < 8; l++){
    const float* Wl = mlp_w + (size_t)l*512*512;
    const float* bl = mlp_b + l*512;
    for(int oo = 0; oo < 2; oo++){
      int o = t + oo*256;
      const float4* wr = (const float4*)(Wl + (size_t)o*512);
      float acc = 0.f;
      #pragma unroll 4
      for(int k = 0; k < 128; k++){
        float4 w4 = wr[k];
        acc += w4.x*xb[4*k] + w4.y*xb[4*k+1] + w4.z*xb[4*k+2] + w4.w*xb[4*k+3];
      }
      yb[o] = lrelu_s2(acc*INV_SQRT512 + bl[o]*0.01f);
    }
    __syncthreads();
    xb[t] = yb[t]; xb[t+256] = yb[t+256];
    __syncthreads();
  }
  wlat[b*512+t] = xb[t]; wlat[b*512+t+256] = xb[t+256];
}

// ---------------- styles: s' for 9 conv layers + 5 torgb layers -------------
__global__ void k_styles(const float* __restrict__ wlat,
                         const float* __restrict__ csw, const float* __restrict__ csb,
                         const float* __restrict__ tsw, const float* __restrict__ tsb,
                         float* __restrict__ s_conv, float* __restrict__ s_trgb){
  int gid = blockIdx.x*256 + threadIdx.x;        // 14*32*512 = 229376 exactly
  int l = gid >> 14;
  int b = (gid >> 9) & 31;
  int i = gid & 511;
  const float* row; float bias, wsc;
  if(l < 9){ row = csw + ((size_t)l*512 + i)*512; bias = csb[l*512+i]; wsc = INV_SQRT4608; }
  else     { int lt = l-9; row = tsw + ((size_t)lt*512 + i)*512; bias = tsb[lt*512+i]; wsc = INV_SQRT512; }
  const float4* r4 = (const float4*)row;
  const float4* w4 = (const float4*)(wlat + b*512);
  float acc = 0.f;
  #pragma unroll 4
  for(int k = 0; k < 128; k++){
    float4 a = w4[k], c = r4[k];
    acc += a.x*c.x + a.y*c.y + a.z*c.z + a.w*c.w;
  }
  float s = (acc*INV_SQRT512 + bias) * wsc;
  if(l < 9) s_conv[((size_t)l*32 + b)*512 + i] = s;
  else      s_trgb[((size_t)(l-9)*32 + b)*512 + i] = s;
}

// ---------------- fused: wsq[l,o,i] = sum w^2; wB[l][tap][o][i] = bf16(w) ----
__global__ void k_prep(const float* __restrict__ cw, float* __restrict__ wsq,
                       bf16* __restrict__ wB){
  int gid = blockIdx.x*256 + threadIdx.x;        // 9*512*512; (l,o,i)
  const float* p = cw + (size_t)gid*9;
  int l = gid >> 18;
  int oi = gid & 0x3ffff;                        // o*512 + i
  float v[9]; float a = 0.f;
  #pragma unroll
  for(int t = 0; t < 9; t++){ v[t] = p[t]; a += v[t]*v[t]; }
  wsq[gid] = a;
  #pragma unroll
  for(int tap = 0; tap < 9; tap++)
    wB[((size_t)(l*9 + tap) << 18) + oi] = __float2bfloat16(v[tap]);
}

// ---------------- demod d[l,b,o] ---------------------------------------------
__global__ void k_demod(const float* __restrict__ s_conv, const float* __restrict__ wsq,
                        float* __restrict__ d_conv){
  __shared__ float s2[512];
  int l = blockIdx.x/32, b = blockIdx.x%32, t = threadIdx.x;
  size_t base = ((size_t)l*32 + b)*512;
  float v0 = s_conv[base + t], v1 = s_conv[base + t + 256];
  s2[t] = v0*v0; s2[t+256] = v1*v1;
  __syncthreads();
  for(int oo = 0; oo < 2; oo++){
    int o = t + oo*256;
    const float4* wr = (const float4*)(wsq + ((size_t)l*512 + o)*512);
    float acc = 0.f;
    #pragma unroll 4
    for(int k = 0; k < 128; k++){
      float4 w = wr[k];
      acc += w.x*s2[4*k] + w.y*s2[4*k+1] + w.z*s2[4*k+2] + w.w*s2[4*k+3];
    }
    d_conv[base + o] = rsqrtf(acc + 1e-8f);
  }
}

// ---------------- torgb compensation ratio ----------------------------------
__global__ void k_ratio(const float* __restrict__ s_conv, const float* __restrict__ s_trgb,
                        float* __restrict__ rat){
  int gid = blockIdx.x*256 + threadIdx.x;        // 5*32*512 = 81920
  int lt = gid >> 14;
  if(lt >= 4){ rat[gid] = 1.0f; return; }
  int b = (gid >> 9) & 31;
  int i = gid & 511;
  int cl = 1 + 2*lt;                             // consuming conv layer
  float st = s_trgb[((size_t)lt*32 + b)*512 + i];
  float sc = s_conv[((size_t)cl*32 + b)*512 + i];
  rat[gid] = (sc != 0.f) ? st/sc : 0.f;
}

// ---------------- const input -> act0 (B,4,4,512) pre-scaled by s_conv[0] ----
__global__ void k_init(const float* __restrict__ ci, const float* __restrict__ s_conv,
                       bf16* __restrict__ act){
  int gid = blockIdx.x*256 + threadIdx.x;        // 32*16*512 = 262144
  int c = gid & 511; int px = (gid >> 9) & 15; int b = gid >> 13;
  act[gid] = __float2bfloat16(ci[c*16 + px] * s_conv[b*512 + c]);
}

// ---------------- conv 128x128: async global_load_lds pipeline ---------------
template<bool UP>
__global__ __launch_bounds__(256, 2)
void k_conv(const bf16* __restrict__ act, const bf16* __restrict__ wL,
            const float* __restrict__ dL, const float* __restrict__ noise,
            const float* __restrict__ nw_ptr, const float* __restrict__ ab,
            const float* __restrict__ sN, bf16* __restrict__ outp,
            const bf16* __restrict__ zp, int Hin, int Mblocks){
  const int q8 = gridDim.x >> 3;
  const int swzb = (blockIdx.x & 7)*q8 + (blockIdx.x >> 3);
  const int nb = swzb & 3, mb = swzb >> 2;
  if(mb >= Mblocks) return;
  const int mbase = mb*128, nbase = nb*128;

  int py = 0, px = 0;
  int OHy, OHx;
  if(UP){
    int cls = blockIdx.z; py = cls >> 1; px = cls & 1;
    OHy = Hin + 1 - py; OHx = Hin + 1 - px;
  } else {
    OHy = Hin; OHx = Hin;
  }
  const int pixN = OHy*OHx;
  const int Mtot = NB*pixN;
  if(mbase >= Mtot) return;

  __shared__ short As[2][128*64];
  __shared__ short Bs[2][128*64];
  const int t = threadIdx.x;
  const int wid  = t >> 6;
  const int lane = t & 63;
  const int rloc = lane >> 3;
  const int slot = lane & 7;

  int swz[4]; int gbv[4], gYv[4], gXv[4]; bool mv[4];
  const bf16* bB[4];
  #pragma unroll
  for(int i = 0; i < 4; i++){
    int r = wid*32 + i*8 + rloc;
    swz[i] = slot ^ (r & 7);
    int m = mbase + r; mv[i] = (m < Mtot); int mm = mv[i] ? m : 0;
    gbv[i] = mm / pixN; int rem = mm % pixN; gYv[i] = rem / OHx; gXv[i] = rem % OHx;
    bB[i] = wL + ((size_t)(nbase + r) << 9) + swz[i]*8;
  }

  const int mrow0 = (wid >> 1)*64;
  const int ncol0 = (wid & 1)*64;
  const int lr = t & 15;
  const int ks = (t & 63) >> 4;
  const int lr7 = lr & 7;
  const int sw0 = (ks ^ lr7)*8;
  const int sw1 = ((4 + ks) ^ lr7)*8;

  f32x4 acc[4][4];
  #pragma unroll
  for(int i = 0; i < 4; i++)
    #pragma unroll
    for(int j = 0; j < 4; j++) acc[i][j] = (f32x4){0.f,0.f,0.f,0.f};

  int dyl[3], dxl[3], ndy, ndx;
  if(UP){
    if(py == 0){ dyl[0]=0; dyl[1]=2; ndy=2; } else { dyl[0]=1; ndy=1; }
    if(px == 0){ dxl[0]=0; dxl[1]=2; ndx=2; } else { dxl[0]=1; ndx=1; }
  } else {
    dyl[0]=0; dyl[1]=1; dyl[2]=2; ndy=3;
    dxl[0]=0; dxl[1]=1; dxl[2]=2; ndx=3;
  }
  const int TT = ndy*ndx;

  auto mkA = [&](int dy, int dx, const bf16** aA){
    #pragma unroll
    for(int i = 0; i < 4; i++){
      int yy, xx;
      if(UP){ yy = gYv[i] - ((dy - py) >> 1); xx = gXv[i] - ((dx - px) >> 1); }
      else  { yy = gYv[i] + dy - 1;           xx = gXv[i] + dx - 1; }
      bool ok = mv[i] && ((unsigned)yy < (unsigned)Hin) && ((unsigned)xx < (unsigned)Hin);
      aA[i] = ok ? (act + (((size_t)((gbv[i]*Hin + yy)*Hin + xx)) << 9) + swz[i]*8) : zp;
    }
  };
  auto issue = [&](const bf16** aA, int tapIdx, int c, int bb){
    #pragma unroll
    for(int i = 0; i < 4; i++)
      GLOAD_LDS16(aA[i] + c*64, &As[bb][(wid*32 + i*8)*64]);
    #pragma unroll
    for(int i = 0; i < 4; i++)
      GLOAD_LDS16(bB[i] + ((size_t)tapIdx << 18) + c*64, &Bs[bb][(wid*32 + i*8)*64]);
  };

  const bf16* aC[4]; const bf16* aN[4];
  int tapC = dyl[0]*3 + dxl[0], tapN = 0;
  mkA(dyl[0], dxl[0], aC);
  issue(aC, tapC, 0, 0);

  for(int tt = 0; tt < TT; tt++){
    const bool haveNextTap = (tt + 1 < TT);
    if(haveNextTap){
      int dyN = dyl[(tt+1)/ndx], dxN = dxl[(tt+1)%ndx];
      tapN = dyN*3 + dxN;
      mkA(dyN, dxN, aN);
    }
    #pragma unroll
    for(int c = 0; c < 8; c++){
      const int bb = c & 1;
      bool issued = true;
      if(c < 7)               issue(aC, tapC, c+1, bb^1);
      else if(haveNextTap)    issue(aN, tapN, 0,   bb^1);
      else                    issued = false;
      if(issued) asm volatile("s_waitcnt vmcnt(8)" ::: "memory");
      else       asm volatile("s_waitcnt vmcnt(0)" ::: "memory");
      __builtin_amdgcn_s_barrier();
      #pragma unroll
      for(int h = 0; h < 2; h++){
        const int swr = h ? sw1 : sw0;
        bf16x8 af[4], bfr[4];
        #pragma unroll
        for(int f = 0; f < 4; f++){
          af[f]  = *(const bf16x8*)&As[bb][(mrow0 + f*16 + lr)*64 + swr];
          bfr[f] = *(const bf16x8*)&Bs[bb][(ncol0 + f*16 + lr)*64 + swr];
        }
        #pragma unroll
        for(int mf = 0; mf < 4; mf++)
          #pragma unroll
          for(int nf = 0; nf < 4; nf++)
            acc[mf][nf] = __builtin_amdgcn_mfma_f32_16x16x32_bf16(af[mf], bfr[nf], acc[mf][nf], 0, 0, 0);
      }
      asm volatile("s_waitcnt lgkmcnt(0)" ::: "memory");
      __builtin_amdgcn_s_barrier();
    }
    if(haveNextTap){
      #pragma unroll
      for(int i = 0; i < 4; i++) aC[i] = aN[i];
      tapC = tapN;
    }
  }

  const float nwv = UP ? 0.f : *nw_ptr;
  const int U = 2*Hin + 1;
  #pragma unroll
  for(int mf = 0; mf < 4; mf++){
    #pragma unroll
    for(int r = 0; r < 4; r++){
      int me = mbase + mrow0 + mf*16 + ks*4 + r;
      if(me >= Mtot) continue;
      int b = me / pixN; int rem2 = me % pixN; int y = rem2 / OHx, x = rem2 % OHx;
      const float* drow = dL + b*512;
      bf16* orow;
      float nz = 0.f; const float* srow = nullptr;
      if(UP){
        orow = outp + (((size_t)((b*U + 2*y + py))*U + (2*x + px)) << 9);
      } else {
        nz = nwv * noise[(b*OHy + y)*OHx + x];
        srow = sN + b*512;
        orow = outp + ((size_t)me << 9);
      }
      #pragma unroll
      for(int nf = 0; nf < 4; nf++){
        int n = nbase + ncol0 + nf*16 + lr;
        float val = acc[mf][nf][r] * drow[n];
        if(!UP) val = lrelu_s2(val + nz + ab[n]) * srow[n];
        orow[n] = __float2bfloat16(val);
      }
    }
  }
}

// ---------------- conv 256x256: async DMA, 512 thr, 8 waves (non-UP) --------
__global__ __launch_bounds__(512, 1)
void k_conv2(const bf16* __restrict__ act, const bf16* __restrict__ wL,
             const float* __restrict__ dL, const float* __restrict__ noise,
             const float* __restrict__ nw_ptr, const float* __restrict__ ab,
             const float* __restrict__ sN, bf16* __restrict__ outp,
             const bf16* __restrict__ zp, int Hin, int Mblocks){
  const int q8 = gridDim.x >> 3;
  const int swzb = (blockIdx.x & 7)*q8 + (blockIdx.x >> 3);
  const int nb = swzb & 1, mb = swzb >> 1;
  if(mb >= Mblocks) return;
  const int mbase = mb*256, nbase = nb*256;
  const int pixN = Hin*Hin;
  const int Mtot = NB*pixN;
  if(mbase >= Mtot) return;

  __shared__ short As[2][256*64];                // 2 x 32 KB
  __shared__ short Bs[2][256*64];                // 2 x 32 KB
  const int t = threadIdx.x;                     // 0..511
  const int wid  = t >> 6;                       // 0..7
  const int lane = t & 63;
  const int rloc = lane >> 3;
  const int slot = lane & 7;

  int swz[4]; int gbv[4], gYv[4], gXv[4]; bool mv[4];
  const bf16* bB[4];
  #pragma unroll
  for(int i = 0; i < 4; i++){
    int r = wid*32 + i*8 + rloc;                 // 0..255
    swz[i] = slot ^ (r & 7);
    int m = mbase + r; mv[i] = (m < Mtot); int mm = mv[i] ? m : 0;
    gbv[i] = mm / pixN; int rem = mm % pixN; gYv[i] = rem / Hin; gXv[i] = rem % Hin;
    bB[i] = wL + ((size_t)(nbase + r) << 9) + swz[i]*8;
  }

  const int mrow0 = (wid >> 2)*128;              // 0 or 128
  const int ncol0 = (wid & 3)*64;                // 0..192
  const int lr = t & 15;
  const int ks = (t & 63) >> 4;
  const int lr7 = lr & 7;
  const int sw0 = (ks ^ lr7)*8;
  const int sw1 = ((4 + ks) ^ lr7)*8;

  f32x4 acc[8][4];
  #pragma unroll
  for(int i = 0; i < 8; i++)
    #pragma unroll
    for(int j = 0; j < 4; j++) acc[i][j] = (f32x4){0.f,0.f,0.f,0.f};

  auto mkA = [&](int dy, int dx, const bf16** aA){
    #pragma unroll
    for(int i = 0; i < 4; i++){
      int yy = gYv[i] + dy - 1, xx = gXv[i] + dx - 1;
      bool ok = mv[i] && ((unsigned)yy < (unsigned)Hin) && ((unsigned)xx < (unsigned)Hin);
      aA[i] = ok ? (act + (((size_t)((gbv[i]*Hin + yy)*Hin + xx)) << 9) + swz[i]*8) : zp;
    }
  };
  auto issue = [&](const bf16** aA, int tapIdx, int c, int bb){
    #pragma unroll
    for(int i = 0; i < 4; i++)
      GLOAD_LDS16(aA[i] + c*64, &As[bb][(wid*32 + i*8)*64]);
    #pragma unroll
    for(int i = 0; i < 4; i++)
      GLOAD_LDS16(bB[i] + ((size_t)tapIdx << 18) + c*64, &Bs[bb][(wid*32 + i*8)*64]);
  };

  const bf16* aC[4]; const bf16* aN[4];
  int tapC = 0, tapN = 0;
  mkA(0, 0, aC);
  issue(aC, 0, 0, 0);

  for(int tt = 0; tt < 9; tt++){
    const bool haveNextTap = (tt + 1 < 9);
    if(haveNextTap){
      int dyN = (tt+1)/3, dxN = (tt+1)%3;
      tapN = tt + 1;
      mkA(dyN, dxN, aN);
    }
    #pragma unroll
    for(int c = 0; c < 8; c++){
      const int bb = c & 1;
      bool issued = true;
      if(c < 7)               issue(aC, tapC, c+1, bb^1);
      else if(haveNextTap)    issue(aN, tapN, 0,   bb^1);
      else                    issued = false;
      if(issued) asm volatile("s_waitcnt vmcnt(8)" ::: "memory");
      else       asm volatile("s_waitcnt vmcnt(0)" ::: "memory");
      __builtin_amdgcn_s_barrier();
      #pragma unroll
      for(int h = 0; h < 2; h++){
        const int swr = h ? sw1 : sw0;
        bf16x8 af[8], bfr[4];
        #pragma unroll
        for(int f = 0; f < 8; f++)
          af[f]  = *(const bf16x8*)&As[bb][(mrow0 + f*16 + lr)*64 + swr];
        #pragma unroll
        for(int f = 0; f < 4; f++)
          bfr[f] = *(const bf16x8*)&Bs[bb][(ncol0 + f*16 + lr)*64 + swr];
        #pragma unroll
        for(int mf = 0; mf < 8; mf++)
          #pragma unroll
          for(int nf = 0; nf < 4; nf++)
            acc[mf][nf] = __builtin_amdgcn_mfma_f32_16x16x32_bf16(af[mf], bfr[nf], acc[mf][nf], 0, 0, 0);
      }
      asm volatile("s_waitcnt lgkmcnt(0)" ::: "memory");
      __builtin_amdgcn_s_barrier();
    }
    if(haveNextTap){
      #pragma unroll
      for(int i = 0; i < 4; i++) aC[i] = aN[i];
      tapC = tapN;
    }
  }

  const float nwv = *nw_ptr;
  #pragma unroll
  for(int mf = 0; mf < 8; mf++){
    #pragma unroll
    for(int r = 0; r < 4; r++){
      int me = mbase + mrow0 + mf*16 + ks*4 + r;
      if(me >= Mtot) continue;
      int b = me / pixN; int rem2 = me % pixN; int y = rem2 / Hin, x = rem2 % Hin;
      const float* drow = dL + b*512;
      float nz = nwv * noise[(b*Hin + y)*Hin + x];
      const float* srow = sN + b*512;
      bf16* orow = outp + ((size_t)me << 9);
      #pragma unroll
      for(int nf = 0; nf < 4; nf++){
        int n = nbase + ncol0 + nf*16 + lr;
        float val = acc[mf][nf][r] * drow[n];
        val = lrelu_s2(val + nz + ab[n]) * srow[n];
        orow[n] = __float2bfloat16(val);
      }
    }
  }
}

// ------ fused separable blur: V pass -> LDS row buffer -> H pass + epilogue --
__global__ void k_blurF(const bf16* __restrict__ u, const float* __restrict__ noise,
                        const float* __restrict__ nw_ptr, const float* __restrict__ ab,
                        const float* __restrict__ sN, bf16* __restrict__ act, int O){
  const int U = O + 1;
  __shared__ unsigned vrow[65*64];               // U x 64 uint (128 bf16 ch)
  const int bid = blockIdx.x;
  const int cq = bid & 3;
  const int rowid = bid >> 2;
  const int Y = rowid % O; const int b = rowid / O;
  const int t = threadIdx.x;
  const int ch2 = t & 63;
  const int cg  = t >> 6;
  const float k1[4] = {0.25f, 0.75f, 0.75f, 0.25f};

  for(int it = 0; it < (65 + 3)/4; it++){
    int col = it*4 + cg;
    if(col < U){
      float a0 = 0.f, a1 = 0.f;
      #pragma unroll
      for(int ky = 0; ky < 4; ky++){
        int yy = Y + ky - 1; if(yy < 0 || yy >= U) continue;
        unsigned uv = *(const unsigned*)(u + (((size_t)(b*U + yy)*U + col) << 9) + cq*128 + ch2*2);
        a0 += k1[ky]*bf_lo(uv); a1 += k1[ky]*bf_hi(uv);
      }
      vrow[col*64 + ch2] = packbf2(a0, a1);
    }
  }
  __syncthreads();
  const float nwv = *nw_ptr;
  const float abA = ab[cq*128 + ch2*2], abB = ab[cq*128 + ch2*2 + 1];
  const float sA  = sN[b*512 + cq*128 + ch2*2], sB = sN[b*512 + cq*128 + ch2*2 + 1];
  for(int it = 0; it < (64 + 3)/4; it++){
    int X = it*4 + cg;
    if(X < O){
      float a0 = 0.f, a1 = 0.f;
      #pragma unroll
      for(int kx = 0; kx < 4; kx++){
        int xx = X + kx - 1; if(xx < 0 || xx >= U) continue;
        unsigned v = vrow[xx*64 + ch2];
        a0 += k1[kx]*bf_lo(v); a1 += k1[kx]*bf_hi(v);
      }
      float nz = nwv * noise[(b*O + Y)*O + X];
      unsigned pk = packbf2(lrelu_s2(a0 + nz + abA)*sA, lrelu_s2(a1 + nz + abB)*sB);
      *(unsigned*)(act + (((size_t)(b*O + Y)*O + X) << 9) + cq*128 + ch2*2) = pk;
    }
  }
}

// ---------------- toRGB (1x1 mod conv, no demod) -> NCHW skip ----------------
__global__ void k_torgb(const bf16* __restrict__ act, const float* __restrict__ tw,
                        const float* __restrict__ ratL, const float* __restrict__ tbias,
                        float* __restrict__ dst, int H, int lt, int addflag){
  int wid = threadIdx.x >> 6, lane = threadIdx.x & 63;
  int pix = blockIdx.x*4 + wid;
  int npix = NB*H*H;
  if(pix >= npix) return;
  int b = pix/(H*H);
  const bf16* ap = act + ((size_t)pix << 9);
  const float* rp = ratL + (size_t)b*512;
  const float* w0 = tw + ((size_t)lt*3 + 0)*512;
  const float* w1 = tw + ((size_t)lt*3 + 1)*512;
  const float* w2 = tw + ((size_t)lt*3 + 2)*512;
  float a0 = 0.f, a1 = 0.f, a2 = 0.f;
  #pragma unroll
  for(int j = 0; j < 8; j++){
    int i = lane + j*64;
    float xs = __bfloat162float(ap[i])*rp[i];
    a0 += xs*w0[i]; a1 += xs*w1[i]; a2 += xs*w2[i];
  }
  for(int off = 32; off > 0; off >>= 1){
    a0 += __shfl_xor(a0, off);
    a1 += __shfl_xor(a1, off);
    a2 += __shfl_xor(a2, off);
  }
  if(lane == 0){
    int rem = pix % (H*H);
    size_t o0 = ((size_t)(b*3 + 0)*H*H) + rem;
    size_t o1 = ((size_t)(b*3 + 1)*H*H) + rem;
    size_t o2 = ((size_t)(b*3 + 2)*H*H) + rem;
    float b0 = tbias[lt*3+0], b1 = tbias[lt*3+1], b2 = tbias[lt*3+2];
    if(addflag){ dst[o0] += a0 + b0; dst[o1] += a1 + b1; dst[o2] += a2 + b2; }
    else       { dst[o0]  = a0 + b0; dst[o1]  = a1 + b1; dst[o2]  = a2 + b2; }
  }
}

// ---------------- skip upsample 2x (NCHW, 3ch) -------------------------------
__global__ void k_skipup(const float* __restrict__ sin, float* __restrict__ sout, int h){
  const int O = 2*h;
  int gid = blockIdx.x*256 + threadIdx.x;
  int total = NB*3*O*O;
  if(gid >= total) return;
  int X = gid % O; int Y = (gid/O) % O; int c = (gid/(O*O)) % 3; int b = gid/(3*O*O);
  const float k1[4] = {1.f, 3.f, 3.f, 1.f};
  float acc = 0.f;
  for(int ky = (Y & 1); ky < 4; ky += 2){
    int ty = Y + ky - 2;
    if(ty < 0) continue;
    int y = ty >> 1; if(y >= h) continue;
    for(int kx = (X & 1); kx < 4; kx += 2){
      int tx = X + kx - 2;
      if(tx < 0) continue;
      int x = tx >> 1; if(x >= h) continue;
      acc += k1[ky]*k1[kx]*(1.f/16.f) * sin[((size_t)(b*3 + c)*h + y)*h + x];
    }
  }
  sout[gid] = acc;
}

// ---------------------------------------------------------------------------
extern "C" void kernel_launch(void* const* d_in, const int* in_sizes, int n_in,
                              void* d_out, int out_size, void* d_ws, size_t ws_size,
                              hipStream_t stream){
  const float* z     = (const float*)d_in[0];
  const float* mlp_w = (const float*)d_in[1];
  const float* mlp_b = (const float*)d_in[2];
  const float* cinp  = (const float*)d_in[3];
  const float* conv_w= (const float*)d_in[4];
  const float* csw   = (const float*)d_in[5];
  const float* csb   = (const float*)d_in[6];
  const float* nwp   = (const float*)d_in[7];
  const float* abp   = (const float*)d_in[8];
  const float* tw    = (const float*)d_in[9];
  const float* tsw   = (const float*)d_in[10];
  const float* tsb   = (const float*)d_in[11];
  const float* tb    = (const float*)d_in[12];
  const float* noise[9];
  for(int i = 0; i < 9; i++) noise[i] = (const float*)d_in[13 + i];

  // workspace layout (bytes)
  const size_t UMAX = (size_t)32*65*65*512;       // 69,206,016 elems
  char* base = (char*)d_ws;
  size_t off = 0;
  bf16* buf0 = (bf16*)(base + off); off += UMAX*2;                 // 138,412,032
  bf16* buf1 = (bf16*)(base + off); off += UMAX*2;                 // 138,412,032
  bf16* wB   = (bf16*)(base + off); off += (size_t)9*9*512*512*2;  //  42,467,328
  float* wsq = (float*)(base + off); off += (size_t)9*512*512*4;   //   9,437,184
  float* wlat= (float*)(base + off); off += (size_t)32*512*4;
  float* sconv=(float*)(base + off); off += (size_t)9*32*512*4;
  float* dconv=(float*)(base + off); off += (size_t)9*32*512*4;
  float* strgb=(float*)(base + off); off += (size_t)5*32*512*4;
  float* rat  =(float*)(base + off); off += (size_t)5*32*512*4;
  float* skipA=(float*)(base + off); off += (size_t)32*3*64*64*4;
  float* skipB=(float*)(base + off); off += (size_t)32*3*64*64*4;
  bf16* zpage=(bf16*)(base + off); off += 2048;                    // zero page
  if(ws_size < off){
    fprintf(stderr, "kernel_launch: ws too small (%zu < %zu)\n", ws_size, off);
    return;
  }
  float* out = (float*)d_out;

  // prep
  hipMemsetAsync(zpage, 0, 2048, stream);
  k_mapping<<<32, 256, 0, stream>>>(z, mlp_w, mlp_b, wlat);
  k_styles <<<896, 256, 0, stream>>>(wlat, csw, csb, tsw, tsb, sconv, strgb);
  k_prep   <<<9216, 256, 0, stream>>>(conv_w, wsq, wB);
  k_demod  <<<288, 256, 0, stream>>>(sconv, wsq, dconv);
  k_ratio  <<<320, 256, 0, stream>>>(sconv, strgb, rat);
  k_init   <<<1024, 256, 0, stream>>>(cinp, sconv, buf0);

  auto conv_noup = [&](const bf16* in, bf16* o, int H, int layer, const float* sN){
    if(H >= 16){
      int M = 32*H*H; int Mb = (M + 255)/256;
      int Gx = ((Mb*2 + 7)/8)*8;
      k_conv2<<<dim3(Gx,1,1), 512, 0, stream>>>(in, wB + ((size_t)layer*9 << 18),
          dconv + (size_t)layer*NB*512, noise[layer], nwp + layer, abp + layer*512, sN, o, zpage, H, Mb);
    } else {
      int M = 32*H*H; int Mb = (M + 127)/128;
      int Gx = ((Mb*4 + 7)/8)*8;
      k_conv<false><<<dim3(Gx,1,1), 256, 0, stream>>>(in, wB + ((size_t)layer*9 << 18),
          dconv + (size_t)layer*NB*512, noise[layer], nwp + layer, abp + layer*512, sN, o, zpage, H, Mb);
    }
  };
  auto conv_up = [&](const bf16* in, bf16* o, int Hin, int layer){
    int Mmax = 32*(Hin+1)*(Hin+1); int Mb = (Mmax + 127)/128;
    int Gx = ((Mb*4 + 7)/8)*8;
    k_conv<true><<<dim3(Gx,1,4), 256, 0, stream>>>(in, wB + ((size_t)layer*9 << 18),
        dconv + (size_t)layer*NB*512, nullptr, nullptr, nullptr, nullptr, o, zpage, Hin, Mb);
  };
  auto blur = [&](const bf16* u, bf16* o, int O, int layer, const float* sN){
    int blocks = 32*O*4;
    k_blurF<<<blocks, 256, 0, stream>>>(u, noise[layer], nwp + layer,
        abp + layer*512, sN, o, O);
  };
  auto torgb = [&](const bf16* act, float* dst, int H, int lt, int add){
    int npix = 32*H*H;
    k_torgb<<<(npix + 3)/4, 256, 0, stream>>>(act, tw, rat + (size_t)lt*NB*512, tb, dst, H, lt, add);
  };
  auto skipup = [&](const float* sin, float* sout, int h){
    int total = 32*3*(2*h)*(2*h);
    k_skipup<<<(total + 255)/256, 256, 0, stream>>>(sin, sout, h);
  };

  const float* S = sconv;   // s rows per layer: S + layer*NB*512
  const float* sT4 = strgb + (size_t)4*NB*512;

  // layer 0 @4   (buf0 = act0; output scaled by s1)
  conv_noup(buf0, buf1, 4, 0, S + (size_t)1*NB*512);   // buf0 -> buf1
  torgb(buf1, skipA, 4, 0, 0);

  // r=0: 4->8
  conv_up(buf1, buf0, 4, 1);                            // buf1 -> buf0 (u)
  blur(buf0, buf1, 8, 1, S + (size_t)2*NB*512);         // buf0 -> buf1 (act8)
  conv_noup(buf1, buf0, 8, 2, S + (size_t)3*NB*512);    // buf1 -> buf0
  skipup(skipA, skipB, 4);
  torgb(buf0, skipB, 8, 1, 1);

  // r=1: 8->16
  conv_up(buf0, buf1, 8, 3);
  blur(buf1, buf0, 16, 3, S + (size_t)4*NB*512);
  conv_noup(buf0, buf1, 16, 4, S + (size_t)5*NB*512);
  skipup(skipB, skipA, 8);
  torgb(buf1, skipA, 16, 2, 1);

  // r=2: 16->32
  conv_up(buf1, buf0, 16, 5);
  blur(buf0, buf1, 32, 5, S + (size_t)6*NB*512);
  conv_noup(buf1, buf0, 32, 6, S + (size_t)7*NB*512);
  skipup(skipA, skipB, 16);
  torgb(buf0, skipB, 32, 3, 1);

  // r=3: 32->64
  conv_up(buf0, buf1, 32, 7);
  blur(buf1, buf0, 64, 7, S + (size_t)8*NB*512);
  conv_noup(buf0, buf1, 64, 8, sT4);                    // last conv: scale by s_trgb4
  skipup(skipB, out, 32);                               // overwrite d_out (poison-safe)
  torgb(buf1, out, 64, 4, 1);                           // final skip add -> d_out
}

// Round 17
// 2086.892 us; speedup vs baseline: 1.0744x; 1.0744x over previous
//
#include <hip/hip_runtime.h>
#include <hip/hip_bf16.h>
#include <cstdio>
#include <math.h>

// ---------------------------------------------------------------------------
// StyleGANv2 generator forward. bf16 MFMA implicit-GEMM convolutions.
//   mod+demod conv == d[b,o] * conv(x * s'[b,i], w_shared); s' folded into the
//   producer epilogue so GEMM A-operand is a pure bf16 gather.
//   Up-conv: parity-decomposed (blockIdx.z = output parity class).
//   k_conv (final): 128x128, async global_load_lds double-buffer, vmcnt(8)
//   counted waits (loads in flight across barriers), zero-page border reads,
//   XOR-8 swizzle via pre-swizzled global SOURCE addresses. No setprio (R15:
//   -2.5% in lockstep pipeline). 256^2 variants measured slower (R13/R16).
//   k_blurF: fused separable blur (V -> LDS row buffer -> H + epilogue).
//   Structure-family ceiling: 36-40% MfmaUtil across 4 schedule variants.
// ---------------------------------------------------------------------------

static constexpr int NB = 32;
static constexpr float SQRT2F      = 1.41421356237309515f;
static constexpr float INV_SQRT512 = 0.04419417382415922f;   // 1/sqrt(512)
static constexpr float INV_SQRT4608= 0.014731391274719742f;  // 1/sqrt(512*9)

typedef __hip_bfloat16 bf16;
typedef __attribute__((ext_vector_type(8))) short bf16x8;
typedef __attribute__((ext_vector_type(4))) float f32x4;

#define GLOAD_LDS16(src, dst) __builtin_amdgcn_global_load_lds( \
    (const __attribute__((address_space(1))) void*)(src), \
    (__attribute__((address_space(3))) void*)(dst), 16, 0, 0)

__device__ __forceinline__ float lrelu_s2(float v){ return (v > 0.f ? v : 0.2f*v) * SQRT2F; }
__device__ __forceinline__ float bf_lo(unsigned u){ unsigned v = u << 16; return __builtin_bit_cast(float, v); }
__device__ __forceinline__ float bf_hi(unsigned u){ unsigned v = u & 0xffff0000u; return __builtin_bit_cast(float, v); }
__device__ __forceinline__ unsigned packbf2(float a, float b){
  bf16 ha = __float2bfloat16(a), hb = __float2bfloat16(b);
  unsigned short ra = __builtin_bit_cast(unsigned short, ha);
  unsigned short rb = __builtin_bit_cast(unsigned short, hb);
  return (unsigned)ra | ((unsigned)rb << 16);
}

// ---------------- mapping network: pixel_norm + 8x (512x512 lrelu) ----------
__global__ void k_mapping(const float* __restrict__ z, const float* __restrict__ mlp_w,
                          const float* __restrict__ mlp_b, float* __restrict__ wlat){
  __shared__ float xb[512], yb[512], red[256];
  int b = blockIdx.x, t = threadIdx.x;
  float z0 = z[b*512 + t], z1 = z[b*512 + t + 256];
  red[t] = z0*z0 + z1*z1;
  __syncthreads();
  for(int s = 128; s > 0; s >>= 1){ if(t < s) red[t] += red[t+s]; __syncthreads(); }
  float norm = sqrtf(red[0]) * INV_SQRT512;
  float inv = 1.f / (norm + 1e-6f);
  xb[t] = z0*inv; xb[t+256] = z1*inv;
  __syncthreads();
  for(int l = 0; l < 8; l++){
    const float* Wl = mlp_w + (size_t)l*512*512;
    const float* bl = mlp_b + l*512;
    for(int oo = 0; oo < 2; oo++){
      int o = t + oo*256;
      const float4* wr = (const float4*)(Wl + (size_t)o*512);
      float acc = 0.f;
      #pragma unroll 4
      for(int k = 0; k < 128; k++){
        float4 w4 = wr[k];
        acc += w4.x*xb[4*k] + w4.y*xb[4*k+1] + w4.z*xb[4*k+2] + w4.w*xb[4*k+3];
      }
      yb[o] = lrelu_s2(acc*INV_SQRT512 + bl[o]*0.01f);
    }
    __syncthreads();
    xb[t] = yb[t]; xb[t+256] = yb[t+256];
    __syncthreads();
  }
  wlat[b*512+t] = xb[t]; wlat[b*512+t+256] = xb[t+256];
}

// ---------------- styles: s' for 9 conv layers + 5 torgb layers -------------
__global__ void k_styles(const float* __restrict__ wlat,
                         const float* __restrict__ csw, const float* __restrict__ csb,
                         const float* __restrict__ tsw, const float* __restrict__ tsb,
                         float* __restrict__ s_conv, float* __restrict__ s_trgb){
  int gid = blockIdx.x*256 + threadIdx.x;        // 14*32*512 = 229376 exactly
  int l = gid >> 14;
  int b = (gid >> 9) & 31;
  int i = gid & 511;
  const float* row; float bias, wsc;
  if(l < 9){ row = csw + ((size_t)l*512 + i)*512; bias = csb[l*512+i]; wsc = INV_SQRT4608; }
  else     { int lt = l-9; row = tsw + ((size_t)lt*512 + i)*512; bias = tsb[lt*512+i]; wsc = INV_SQRT512; }
  const float4* r4 = (const float4*)row;
  const float4* w4 = (const float4*)(wlat + b*512);
  float acc = 0.f;
  #pragma unroll 4
  for(int k = 0; k < 128; k++){
    float4 a = w4[k], c = r4[k];
    acc += a.x*c.x + a.y*c.y + a.z*c.z + a.w*c.w;
  }
  float s = (acc*INV_SQRT512 + bias) * wsc;
  if(l < 9) s_conv[((size_t)l*32 + b)*512 + i] = s;
  else      s_trgb[((size_t)(l-9)*32 + b)*512 + i] = s;
}

// ---------------- fused: wsq[l,o,i] = sum w^2; wB[l][tap][o][i] = bf16(w) ----
__global__ void k_prep(const float* __restrict__ cw, float* __restrict__ wsq,
                       bf16* __restrict__ wB){
  int gid = blockIdx.x*256 + threadIdx.x;        // 9*512*512; (l,o,i)
  const float* p = cw + (size_t)gid*9;
  int l = gid >> 18;
  int oi = gid & 0x3ffff;                        // o*512 + i
  float v[9]; float a = 0.f;
  #pragma unroll
  for(int t = 0; t < 9; t++){ v[t] = p[t]; a += v[t]*v[t]; }
  wsq[gid] = a;
  #pragma unroll
  for(int tap = 0; tap < 9; tap++)
    wB[((size_t)(l*9 + tap) << 18) + oi] = __float2bfloat16(v[tap]);
}

// ---------------- demod d[l,b,o] ---------------------------------------------
__global__ void k_demod(const float* __restrict__ s_conv, const float* __restrict__ wsq,
                        float* __restrict__ d_conv){
  __shared__ float s2[512];
  int l = blockIdx.x/32, b = blockIdx.x%32, t = threadIdx.x;
  size_t base = ((size_t)l*32 + b)*512;
  float v0 = s_conv[base + t], v1 = s_conv[base + t + 256];
  s2[t] = v0*v0; s2[t+256] = v1*v1;
  __syncthreads();
  for(int oo = 0; oo < 2; oo++){
    int o = t + oo*256;
    const float4* wr = (const float4*)(wsq + ((size_t)l*512 + o)*512);
    float acc = 0.f;
    #pragma unroll 4
    for(int k = 0; k < 128; k++){
      float4 w = wr[k];
      acc += w.x*s2[4*k] + w.y*s2[4*k+1] + w.z*s2[4*k+2] + w.w*s2[4*k+3];
    }
    d_conv[base + o] = rsqrtf(acc + 1e-8f);
  }
}

// ---------------- torgb compensation ratio ----------------------------------
__global__ void k_ratio(const float* __restrict__ s_conv, const float* __restrict__ s_trgb,
                        float* __restrict__ rat){
  int gid = blockIdx.x*256 + threadIdx.x;        // 5*32*512 = 81920
  int lt = gid >> 14;
  if(lt >= 4){ rat[gid] = 1.0f; return; }
  int b = (gid >> 9) & 31;
  int i = gid & 511;
  int cl = 1 + 2*lt;                             // consuming conv layer
  float st = s_trgb[((size_t)lt*32 + b)*512 + i];
  float sc = s_conv[((size_t)cl*32 + b)*512 + i];
  rat[gid] = (sc != 0.f) ? st/sc : 0.f;
}

// ---------------- const input -> act0 (B,4,4,512) pre-scaled by s_conv[0] ----
__global__ void k_init(const float* __restrict__ ci, const float* __restrict__ s_conv,
                       bf16* __restrict__ act){
  int gid = blockIdx.x*256 + threadIdx.x;        // 32*16*512 = 262144
  int c = gid & 511; int px = (gid >> 9) & 15; int b = gid >> 13;
  act[gid] = __float2bfloat16(ci[c*16 + px] * s_conv[b*512 + c]);
}

// ---------------- conv 128x128: async global_load_lds pipeline ---------------
template<bool UP>
__global__ __launch_bounds__(256, 2)
void k_conv(const bf16* __restrict__ act, const bf16* __restrict__ wL,
            const float* __restrict__ dL, const float* __restrict__ noise,
            const float* __restrict__ nw_ptr, const float* __restrict__ ab,
            const float* __restrict__ sN, bf16* __restrict__ outp,
            const bf16* __restrict__ zp, int Hin, int Mblocks){
  const int q8 = gridDim.x >> 3;
  const int swzb = (blockIdx.x & 7)*q8 + (blockIdx.x >> 3);
  const int nb = swzb & 3, mb = swzb >> 2;
  if(mb >= Mblocks) return;
  const int mbase = mb*128, nbase = nb*128;

  int py = 0, px = 0;
  int OHy, OHx;
  if(UP){
    int cls = blockIdx.z; py = cls >> 1; px = cls & 1;
    OHy = Hin + 1 - py; OHx = Hin + 1 - px;
  } else {
    OHy = Hin; OHx = Hin;
  }
  const int pixN = OHy*OHx;
  const int Mtot = NB*pixN;
  if(mbase >= Mtot) return;

  __shared__ short As[2][128*64];
  __shared__ short Bs[2][128*64];
  const int t = threadIdx.x;
  const int wid  = t >> 6;
  const int lane = t & 63;
  const int rloc = lane >> 3;
  const int slot = lane & 7;

  int swz[4]; int gbv[4], gYv[4], gXv[4]; bool mv[4];
  const bf16* bB[4];
  #pragma unroll
  for(int i = 0; i < 4; i++){
    int r = wid*32 + i*8 + rloc;
    swz[i] = slot ^ (r & 7);
    int m = mbase + r; mv[i] = (m < Mtot); int mm = mv[i] ? m : 0;
    gbv[i] = mm / pixN; int rem = mm % pixN; gYv[i] = rem / OHx; gXv[i] = rem % OHx;
    bB[i] = wL + ((size_t)(nbase + r) << 9) + swz[i]*8;
  }

  const int mrow0 = (wid >> 1)*64;
  const int ncol0 = (wid & 1)*64;
  const int lr = t & 15;
  const int ks = (t & 63) >> 4;
  const int lr7 = lr & 7;
  const int sw0 = (ks ^ lr7)*8;
  const int sw1 = ((4 + ks) ^ lr7)*8;

  f32x4 acc[4][4];
  #pragma unroll
  for(int i = 0; i < 4; i++)
    #pragma unroll
    for(int j = 0; j < 4; j++) acc[i][j] = (f32x4){0.f,0.f,0.f,0.f};

  int dyl[3], dxl[3], ndy, ndx;
  if(UP){
    if(py == 0){ dyl[0]=0; dyl[1]=2; ndy=2; } else { dyl[0]=1; ndy=1; }
    if(px == 0){ dxl[0]=0; dxl[1]=2; ndx=2; } else { dxl[0]=1; ndx=1; }
  } else {
    dyl[0]=0; dyl[1]=1; dyl[2]=2; ndy=3;
    dxl[0]=0; dxl[1]=1; dxl[2]=2; ndx=3;
  }
  const int TT = ndy*ndx;

  auto mkA = [&](int dy, int dx, const bf16** aA){
    #pragma unroll
    for(int i = 0; i < 4; i++){
      int yy, xx;
      if(UP){ yy = gYv[i] - ((dy - py) >> 1); xx = gXv[i] - ((dx - px) >> 1); }
      else  { yy = gYv[i] + dy - 1;           xx = gXv[i] + dx - 1; }
      bool ok = mv[i] && ((unsigned)yy < (unsigned)Hin) && ((unsigned)xx < (unsigned)Hin);
      aA[i] = ok ? (act + (((size_t)((gbv[i]*Hin + yy)*Hin + xx)) << 9) + swz[i]*8) : zp;
    }
  };
  auto issue = [&](const bf16** aA, int tapIdx, int c, int bb){
    #pragma unroll
    for(int i = 0; i < 4; i++)
      GLOAD_LDS16(aA[i] + c*64, &As[bb][(wid*32 + i*8)*64]);
    #pragma unroll
    for(int i = 0; i < 4; i++)
      GLOAD_LDS16(bB[i] + ((size_t)tapIdx << 18) + c*64, &Bs[bb][(wid*32 + i*8)*64]);
  };

  const bf16* aC[4]; const bf16* aN[4];
  int tapC = dyl[0]*3 + dxl[0], tapN = 0;
  mkA(dyl[0], dxl[0], aC);
  issue(aC, tapC, 0, 0);

  for(int tt = 0; tt < TT; tt++){
    const bool haveNextTap = (tt + 1 < TT);
    if(haveNextTap){
      int dyN = dyl[(tt+1)/ndx], dxN = dxl[(tt+1)%ndx];
      tapN = dyN*3 + dxN;
      mkA(dyN, dxN, aN);
    }
    #pragma unroll
    for(int c = 0; c < 8; c++){
      const int bb = c & 1;
      bool issued = true;
      if(c < 7)               issue(aC, tapC, c+1, bb^1);
      else if(haveNextTap)    issue(aN, tapN, 0,   bb^1);
      else                    issued = false;
      if(issued) asm volatile("s_waitcnt vmcnt(8)" ::: "memory");
      else       asm volatile("s_waitcnt vmcnt(0)" ::: "memory");
      __builtin_amdgcn_s_barrier();
      #pragma unroll
      for(int h = 0; h < 2; h++){
        const int swr = h ? sw1 : sw0;
        bf16x8 af[4], bfr[4];
        #pragma unroll
        for(int f = 0; f < 4; f++){
          af[f]  = *(const bf16x8*)&As[bb][(mrow0 + f*16 + lr)*64 + swr];
          bfr[f] = *(const bf16x8*)&Bs[bb][(ncol0 + f*16 + lr)*64 + swr];
        }
        #pragma unroll
        for(int mf = 0; mf < 4; mf++)
          #pragma unroll
          for(int nf = 0; nf < 4; nf++)
            acc[mf][nf] = __builtin_amdgcn_mfma_f32_16x16x32_bf16(af[mf], bfr[nf], acc[mf][nf], 0, 0, 0);
      }
      asm volatile("s_waitcnt lgkmcnt(0)" ::: "memory");
      __builtin_amdgcn_s_barrier();
    }
    if(haveNextTap){
      #pragma unroll
      for(int i = 0; i < 4; i++) aC[i] = aN[i];
      tapC = tapN;
    }
  }

  const float nwv = UP ? 0.f : *nw_ptr;
  const int U = 2*Hin + 1;
  #pragma unroll
  for(int mf = 0; mf < 4; mf++){
    #pragma unroll
    for(int r = 0; r < 4; r++){
      int me = mbase + mrow0 + mf*16 + ks*4 + r;
      if(me >= Mtot) continue;
      int b = me / pixN; int rem2 = me % pixN; int y = rem2 / OHx, x = rem2 % OHx;
      const float* drow = dL + b*512;
      bf16* orow;
      float nz = 0.f; const float* srow = nullptr;
      if(UP){
        orow = outp + (((size_t)((b*U + 2*y + py))*U + (2*x + px)) << 9);
      } else {
        nz = nwv * noise[(b*OHy + y)*OHx + x];
        srow = sN + b*512;
        orow = outp + ((size_t)me << 9);
      }
      #pragma unroll
      for(int nf = 0; nf < 4; nf++){
        int n = nbase + ncol0 + nf*16 + lr;
        float val = acc[mf][nf][r] * drow[n];
        if(!UP) val = lrelu_s2(val + nz + ab[n]) * srow[n];
        orow[n] = __float2bfloat16(val);
      }
    }
  }
}

// ------ fused separable blur: V pass -> LDS row buffer -> H pass + epilogue --
__global__ void k_blurF(const bf16* __restrict__ u, const float* __restrict__ noise,
                        const float* __restrict__ nw_ptr, const float* __restrict__ ab,
                        const float* __restrict__ sN, bf16* __restrict__ act, int O){
  const int U = O + 1;
  __shared__ unsigned vrow[65*64];               // U x 64 uint (128 bf16 ch)
  const int bid = blockIdx.x;
  const int cq = bid & 3;
  const int rowid = bid >> 2;
  const int Y = rowid % O; const int b = rowid / O;
  const int t = threadIdx.x;
  const int ch2 = t & 63;
  const int cg  = t >> 6;
  const float k1[4] = {0.25f, 0.75f, 0.75f, 0.25f};

  for(int it = 0; it < (65 + 3)/4; it++){
    int col = it*4 + cg;
    if(col < U){
      float a0 = 0.f, a1 = 0.f;
      #pragma unroll
      for(int ky = 0; ky < 4; ky++){
        int yy = Y + ky - 1; if(yy < 0 || yy >= U) continue;
        unsigned uv = *(const unsigned*)(u + (((size_t)(b*U + yy)*U + col) << 9) + cq*128 + ch2*2);
        a0 += k1[ky]*bf_lo(uv); a1 += k1[ky]*bf_hi(uv);
      }
      vrow[col*64 + ch2] = packbf2(a0, a1);
    }
  }
  __syncthreads();
  const float nwv = *nw_ptr;
  const float abA = ab[cq*128 + ch2*2], abB = ab[cq*128 + ch2*2 + 1];
  const float sA  = sN[b*512 + cq*128 + ch2*2], sB = sN[b*512 + cq*128 + ch2*2 + 1];
  for(int it = 0; it < (64 + 3)/4; it++){
    int X = it*4 + cg;
    if(X < O){
      float a0 = 0.f, a1 = 0.f;
      #pragma unroll
      for(int kx = 0; kx < 4; kx++){
        int xx = X + kx - 1; if(xx < 0 || xx >= U) continue;
        unsigned v = vrow[xx*64 + ch2];
        a0 += k1[kx]*bf_lo(v); a1 += k1[kx]*bf_hi(v);
      }
      float nz = nwv * noise[(b*O + Y)*O + X];
      unsigned pk = packbf2(lrelu_s2(a0 + nz + abA)*sA, lrelu_s2(a1 + nz + abB)*sB);
      *(unsigned*)(act + (((size_t)(b*O + Y)*O + X) << 9) + cq*128 + ch2*2) = pk;
    }
  }
}

// ---------------- toRGB (1x1 mod conv, no demod) -> NCHW skip ----------------
__global__ void k_torgb(const bf16* __restrict__ act, const float* __restrict__ tw,
                        const float* __restrict__ ratL, const float* __restrict__ tbias,
                        float* __restrict__ dst, int H, int lt, int addflag){
  int wid = threadIdx.x >> 6, lane = threadIdx.x & 63;
  int pix = blockIdx.x*4 + wid;
  int npix = NB*H*H;
  if(pix >= npix) return;
  int b = pix/(H*H);
  const bf16* ap = act + ((size_t)pix << 9);
  const float* rp = ratL + (size_t)b*512;
  const float* w0 = tw + ((size_t)lt*3 + 0)*512;
  const float* w1 = tw + ((size_t)lt*3 + 1)*512;
  const float* w2 = tw + ((size_t)lt*3 + 2)*512;
  float a0 = 0.f, a1 = 0.f, a2 = 0.f;
  #pragma unroll
  for(int j = 0; j < 8; j++){
    int i = lane + j*64;
    float xs = __bfloat162float(ap[i])*rp[i];
    a0 += xs*w0[i]; a1 += xs*w1[i]; a2 += xs*w2[i];
  }
  for(int off = 32; off > 0; off >>= 1){
    a0 += __shfl_xor(a0, off);
    a1 += __shfl_xor(a1, off);
    a2 += __shfl_xor(a2, off);
  }
  if(lane == 0){
    int rem = pix % (H*H);
    size_t o0 = ((size_t)(b*3 + 0)*H*H) + rem;
    size_t o1 = ((size_t)(b*3 + 1)*H*H) + rem;
    size_t o2 = ((size_t)(b*3 + 2)*H*H) + rem;
    float b0 = tbias[lt*3+0], b1 = tbias[lt*3+1], b2 = tbias[lt*3+2];
    if(addflag){ dst[o0] += a0 + b0; dst[o1] += a1 + b1; dst[o2] += a2 + b2; }
    else       { dst[o0]  = a0 + b0; dst[o1]  = a1 + b1; dst[o2]  = a2 + b2; }
  }
}

// ---------------- skip upsample 2x (NCHW, 3ch) -------------------------------
__global__ void k_skipup(const float* __restrict__ sin, float* __restrict__ sout, int h){
  const int O = 2*h;
  int gid = blockIdx.x*256 + threadIdx.x;
  int total = NB*3*O*O;
  if(gid >= total) return;
  int X = gid % O; int Y = (gid/O) % O; int c = (gid/(O*O)) % 3; int b = gid/(3*O*O);
  const float k1[4] = {1.f, 3.f, 3.f, 1.f};
  float acc = 0.f;
  for(int ky = (Y & 1); ky < 4; ky += 2){
    int ty = Y + ky - 2;
    if(ty < 0) continue;
    int y = ty >> 1; if(y >= h) continue;
    for(int kx = (X & 1); kx < 4; kx += 2){
      int tx = X + kx - 2;
      if(tx < 0) continue;
      int x = tx >> 1; if(x >= h) continue;
      acc += k1[ky]*k1[kx]*(1.f/16.f) * sin[((size_t)(b*3 + c)*h + y)*h + x];
    }
  }
  sout[gid] = acc;
}

// ---------------------------------------------------------------------------
extern "C" void kernel_launch(void* const* d_in, const int* in_sizes, int n_in,
                              void* d_out, int out_size, void* d_ws, size_t ws_size,
                              hipStream_t stream){
  const float* z     = (const float*)d_in[0];
  const float* mlp_w = (const float*)d_in[1];
  const float* mlp_b = (const float*)d_in[2];
  const float* cinp  = (const float*)d_in[3];
  const float* conv_w= (const float*)d_in[4];
  const float* csw   = (const float*)d_in[5];
  const float* csb   = (const float*)d_in[6];
  const float* nwp   = (const float*)d_in[7];
  const float* abp   = (const float*)d_in[8];
  const float* tw    = (const float*)d_in[9];
  const float* tsw   = (const float*)d_in[10];
  const float* tsb   = (const float*)d_in[11];
  const float* tb    = (const float*)d_in[12];
  const float* noise[9];
  for(int i = 0; i < 9; i++) noise[i] = (const float*)d_in[13 + i];

  // workspace layout (bytes)
  const size_t UMAX = (size_t)32*65*65*512;       // 69,206,016 elems
  char* base = (char*)d_ws;
  size_t off = 0;
  bf16* buf0 = (bf16*)(base + off); off += UMAX*2;                 // 138,412,032
  bf16* buf1 = (bf16*)(base + off); off += UMAX*2;                 // 138,412,032
  bf16* wB   = (bf16*)(base + off); off += (size_t)9*9*512*512*2;  //  42,467,328
  float* wsq = (float*)(base + off); off += (size_t)9*512*512*4;   //   9,437,184
  float* wlat= (float*)(base + off); off += (size_t)32*512*4;
  float* sconv=(float*)(base + off); off += (size_t)9*32*512*4;
  float* dconv=(float*)(base + off); off += (size_t)9*32*512*4;
  float* strgb=(float*)(base + off); off += (size_t)5*32*512*4;
  float* rat  =(float*)(base + off); off += (size_t)5*32*512*4;
  float* skipA=(float*)(base + off); off += (size_t)32*3*64*64*4;
  float* skipB=(float*)(base + off); off += (size_t)32*3*64*64*4;
  bf16* zpage=(bf16*)(base + off); off += 2048;                    // zero page
  if(ws_size < off){
    fprintf(stderr, "kernel_launch: ws too small (%zu < %zu)\n", ws_size, off);
    return;
  }
  float* out = (float*)d_out;

  // prep
  hipMemsetAsync(zpage, 0, 2048, stream);
  k_mapping<<<32, 256, 0, stream>>>(z, mlp_w, mlp_b, wlat);
  k_styles <<<896, 256, 0, stream>>>(wlat, csw, csb, tsw, tsb, sconv, strgb);
  k_prep   <<<9216, 256, 0, stream>>>(conv_w, wsq, wB);
  k_demod  <<<288, 256, 0, stream>>>(sconv, wsq, dconv);
  k_ratio  <<<320, 256, 0, stream>>>(sconv, strgb, rat);
  k_init   <<<1024, 256, 0, stream>>>(cinp, sconv, buf0);

  auto conv_noup = [&](const bf16* in, bf16* o, int H, int layer, const float* sN){
    int M = 32*H*H; int Mb = (M + 127)/128;
    int Gx = ((Mb*4 + 7)/8)*8;
    k_conv<false><<<dim3(Gx,1,1), 256, 0, stream>>>(in, wB + ((size_t)layer*9 << 18),
        dconv + (size_t)layer*NB*512, noise[layer], nwp + layer, abp + layer*512, sN, o, zpage, H, Mb);
  };
  auto conv_up = [&](const bf16* in, bf16* o, int Hin, int layer){
    int Mmax = 32*(Hin+1)*(Hin+1); int Mb = (Mmax + 127)/128;
    int Gx = ((Mb*4 + 7)/8)*8;
    k_conv<true><<<dim3(Gx,1,4), 256, 0, stream>>>(in, wB + ((size_t)layer*9 << 18),
        dconv + (size_t)layer*NB*512, nullptr, nullptr, nullptr, nullptr, o, zpage, Hin, Mb);
  };
  auto blur = [&](const bf16* u, bf16* o, int O, int layer, const float* sN){
    int blocks = 32*O*4;
    k_blurF<<<blocks, 256, 0, stream>>>(u, noise[layer], nwp + layer,
        abp + layer*512, sN, o, O);
  };
  auto torgb = [&](const bf16* act, float* dst, int H, int lt, int add){
    int npix = 32*H*H;
    k_torgb<<<(npix + 3)/4, 256, 0, stream>>>(act, tw, rat + (size_t)lt*NB*512, tb, dst, H, lt, add);
  };
  auto skipup = [&](const float* sin, float* sout, int h){
    int total = 32*3*(2*h)*(2*h);
    k_skipup<<<(total + 255)/256, 256, 0, stream>>>(sin, sout, h);
  };

  const float* S = sconv;   // s rows per layer: S + layer*NB*512
  const float* sT4 = strgb + (size_t)4*NB*512;

  // layer 0 @4   (buf0 = act0; output scaled by s1)
  conv_noup(buf0, buf1, 4, 0, S + (size_t)1*NB*512);   // buf0 -> buf1
  torgb(buf1, skipA, 4, 0, 0);

  // r=0: 4->8
  conv_up(buf1, buf0, 4, 1);                            // buf1 -> buf0 (u)
  blur(buf0, buf1, 8, 1, S + (size_t)2*NB*512);         // buf0 -> buf1 (act8)
  conv_noup(buf1, buf0, 8, 2, S + (size_t)3*NB*512);    // buf1 -> buf0
  skipup(skipA, skipB, 4);
  torgb(buf0, skipB, 8, 1, 1);

  // r=1: 8->16
  conv_up(buf0, buf1, 8, 3);
  blur(buf1, buf0, 16, 3, S + (size_t)4*NB*512);
  conv_noup(buf0, buf1, 16, 4, S + (size_t)5*NB*512);
  skipup(skipB, skipA, 8);
  torgb(buf1, skipA, 16, 2, 1);

  // r=2: 16->32
  conv_up(buf1, buf0, 16, 5);
  blur(buf0, buf1, 32, 5, S + (size_t)6*NB*512);
  conv_noup(buf1, buf0, 32, 6, S + (size_t)7*NB*512);
  skipup(skipA, skipB, 16);
  torgb(buf0, skipB, 32, 3, 1);

  // r=3: 32->64
  conv_up(buf0, buf1, 32, 7);
  blur(buf1, buf0, 64, 7, S + (size_t)8*NB*512);
  conv_noup(buf0, buf1, 64, 8, sT4);                    // last conv: scale by s_trgb4
  skipup(skipB, out, 32);                               // overwrite d_out (poison-safe)
  torgb(buf1, out, 64, 4, 1);                           // final skip add -> d_out
}